// Round 1
// baseline (770.329 us; speedup 1.0000x reference)
//
#include <hip/hip_runtime.h>

#define N_GRID 262144
#define BSZ 128
#define NNZ_TOT 1835008
#define ROWS_PER_BLOCK 32
#define NBLK_FUSED (N_GRID / ROWS_PER_BLOCK)   // 8192
#define PAIR_CAP (NNZ_TOT + 7 * N_GRID)        // padded-to-8 worst case = 3670016

// ws layout (8B-aligned):
//   ypT     : N*BSZ f32          = 128 MB  (y_pred transposed)
//   acc     : 5*128 doubles      = 5120 B  (s1, t2, s2, s3, s4)
//   counts  : N ints             = 1 MB
//   ptr     : N+2 ints           = 1 MB    (padded CSR row pointers)
//   cursor  : N ints             = 1 MB
//   bsums   : 512 ints           = 2 KB
//   pairs   : PAIR_CAP int2      = 29.4 MB (col, bitcast val), row-sorted, zero-padded
//   partial : NBLK_FUSED*640 f32 = 20 MB   (per-block partial sums)

// ---- K1: transpose y_pred (BSZ, N) -> ypT (N, BSZ), float4 both ways ----
__global__ __launch_bounds__(256) void transpose_kernel(const float* __restrict__ yp,
                                                        float* __restrict__ ypT) {
    __shared__ float tile[64 * 65];
    int n0 = blockIdx.x * 64;
    int b0 = blockIdx.y * 64;
    int tx = threadIdx.x & 15;   // 0..15 -> 4 floats each
    int ty = threadIdx.x >> 4;   // 0..15
#pragma unroll
    for (int jj = 0; jj < 4; ++jj) {
        int b = b0 + ty + jj * 16;
        float4 v = *(const float4*)&yp[(size_t)b * N_GRID + n0 + 4 * tx];
        tile[(4 * tx + 0) * 65 + ty + jj * 16] = v.x;
        tile[(4 * tx + 1) * 65 + ty + jj * 16] = v.y;
        tile[(4 * tx + 2) * 65 + ty + jj * 16] = v.z;
        tile[(4 * tx + 3) * 65 + ty + jj * 16] = v.w;
    }
    __syncthreads();
#pragma unroll
    for (int jj = 0; jj < 4; ++jj) {
        int nl = ty + jj * 16;
        float4 v;
        v.x = tile[nl * 65 + 4 * tx + 0];
        v.y = tile[nl * 65 + 4 * tx + 1];
        v.z = tile[nl * 65 + 4 * tx + 2];
        v.w = tile[nl * 65 + 4 * tx + 3];
        *(float4*)&ypT[(size_t)(n0 + nl) * BSZ + b0 + 4 * tx] = v;
    }
}

// ---- K2: histogram of rows ----
__global__ __launch_bounds__(256) void hist_kernel(const int* __restrict__ rows,
                                                   int* __restrict__ counts) {
    int k0 = blockIdx.x * 1024 + threadIdx.x;
    int kend = blockIdx.x * 1024 + 1024;
#pragma unroll
    for (int k = k0; k < kend; k += 256) atomicAdd(&counts[rows[k]], 1);
}

// ---- K3a: per-block exclusive scan of PADDED counts (512 elems/block) ----
__global__ __launch_bounds__(512) void scan1_kernel(const int* __restrict__ counts,
                                                    int* __restrict__ ptr,
                                                    int* __restrict__ bsums) {
    __shared__ int sdata[512];
    int i = blockIdx.x * 512 + threadIdx.x;
    int x = (counts[i] + 7) & ~7;   // pad each row to a multiple of 8
    sdata[threadIdx.x] = x;
    __syncthreads();
    for (int off = 1; off < 512; off <<= 1) {
        int v = 0;
        if ((int)threadIdx.x >= off) v = sdata[threadIdx.x - off];
        __syncthreads();
        sdata[threadIdx.x] += v;
        __syncthreads();
    }
    ptr[i] = sdata[threadIdx.x] - x;
    if (threadIdx.x == 511) bsums[blockIdx.x] = sdata[511];
}

// ---- K3b: exclusive scan of 512 block sums; grand total -> ptr[N] ----
__global__ __launch_bounds__(512) void scan2_kernel(int* __restrict__ bsums,
                                                    int* __restrict__ ptr) {
    __shared__ int sdata[512];
    int x = bsums[threadIdx.x];
    sdata[threadIdx.x] = x;
    __syncthreads();
    for (int off = 1; off < 512; off <<= 1) {
        int v = 0;
        if ((int)threadIdx.x >= off) v = sdata[threadIdx.x - off];
        __syncthreads();
        sdata[threadIdx.x] += v;
        __syncthreads();
    }
    bsums[threadIdx.x] = sdata[threadIdx.x] - x;
    if (threadIdx.x == 511) ptr[N_GRID] = sdata[511];  // total padded count
}

// ---- K3c: add block offsets, init cursors ----
__global__ __launch_bounds__(512) void scan3_kernel(int* __restrict__ ptr,
                                                    int* __restrict__ cursor,
                                                    const int* __restrict__ bsums) {
    int i = blockIdx.x * 512 + threadIdx.x;
    int v = ptr[i] + bsums[blockIdx.x];
    ptr[i] = v;
    cursor[i] = v;
}

// ---- K4: scatter (col,val) pairs into padded CSR slots ----
__global__ __launch_bounds__(256) void csr_scatter_kernel(const float* __restrict__ vals,
                                                          const int* __restrict__ rows,
                                                          const int* __restrict__ cols,
                                                          int* __restrict__ cursor,
                                                          int2* __restrict__ pairs) {
    int k0 = blockIdx.x * 1024 + threadIdx.x;
    int kend = blockIdx.x * 1024 + 1024;
#pragma unroll
    for (int k = k0; k < kend; k += 256) {
        int r = rows[k];
        int pos = atomicAdd(&cursor[r], 1);
        pairs[pos] = make_int2(cols[k], __float_as_int(vals[k]));
    }
}

// ---- K5: fused SpMV + all five per-batch reductions, f32 partials out ----
__global__ __launch_bounds__(256) void fused_kernel(const float* __restrict__ ypT,
                                                    const float* __restrict__ yt,
                                                    const int* __restrict__ ptr,
                                                    const int2* __restrict__ pairs,
                                                    float* __restrict__ partial) {
    __shared__ float ytile[ROWS_PER_BLOCK * 129];
    __shared__ double red[5 * BSZ];
    int b = threadIdx.x & 127;
    int g = threadIdx.x >> 7;  // 0 or 1
    int n0 = blockIdx.x * ROWS_PER_BLOCK;

    for (int idx = threadIdx.x; idx < ROWS_PER_BLOCK * 128; idx += 256) {
        int bb = idx >> 5;
        int j = idx & 31;
        ytile[j * 129 + bb] = yt[(size_t)bb * N_GRID + n0 + j];
    }
    __syncthreads();

    double a1 = 0.0, at2 = 0.0, a2 = 0.0, a3 = 0.0, a4 = 0.0;
    for (int nl = g; nl < ROWS_PER_BLOCK; nl += 2) {
        int n = n0 + nl;
        int e0 = __builtin_amdgcn_readfirstlane(ptr[n]);
        int e1 = __builtin_amdgcn_readfirstlane(ptr[n + 1]);
        float y = 0.0f;
        // padded: (e1 - e0) % 8 == 0; zero entries contribute 0
        for (int e = e0; e < e1; e += 8) {
            int2 q[8];
#pragma unroll
            for (int u = 0; u < 8; ++u) q[u] = pairs[e + u];
            float gv[8];
#pragma unroll
            for (int u = 0; u < 8; ++u) gv[u] = ypT[(size_t)q[u].x * BSZ + b];
#pragma unroll
            for (int u = 0; u < 8; ++u) y = fmaf(__int_as_float(q[u].y), gv[u], y);
        }
        float p = ypT[(size_t)n * BSZ + b];
        float tt = ytile[nl * 129 + b];
        a1 += (double)tt * (double)p;
        at2 += (double)tt * (double)tt;
        a2 += (double)p * (double)y;
        a3 += (double)tt * (double)y;
        a4 += (double)y * (double)y;
    }

    if (g == 1) {
        red[b] = a1; red[BSZ + b] = at2; red[2 * BSZ + b] = a2;
        red[3 * BSZ + b] = a3; red[4 * BSZ + b] = a4;
    }
    __syncthreads();
    if (g == 0) {
        float* pb = partial + (size_t)blockIdx.x * (5 * BSZ);
        pb[b] = (float)(a1 + red[b]);
        pb[BSZ + b] = (float)(at2 + red[BSZ + b]);
        pb[2 * BSZ + b] = (float)(a2 + red[2 * BSZ + b]);
        pb[3 * BSZ + b] = (float)(a3 + red[3 * BSZ + b]);
        pb[4 * BSZ + b] = (float)(a4 + red[4 * BSZ + b]);
    }
}

// ---- K6: reduce partials into acc (grid: (5, 16), 128 threads) ----
__global__ __launch_bounds__(128) void reduce2_kernel(const float* __restrict__ partial,
                                                      double* __restrict__ acc) {
    int s = blockIdx.x;
    int chunk = blockIdx.y;
    int b = threadIdx.x;
    const int PER = NBLK_FUSED / 16;  // 512
    double sum = 0.0;
    int i0 = chunk * PER;
#pragma unroll 4
    for (int i = 0; i < PER; ++i) {
        sum += (double)partial[(size_t)(i0 + i) * (5 * BSZ) + s * BSZ + b];
    }
    atomicAdd(&acc[s * BSZ + b], sum);
}

// ---- K7: loss_b = t2 - 2*scale*s3 + scale^2*s4; out = mean_b ----
__global__ __launch_bounds__(128) void finalize_kernel(const double* __restrict__ acc,
                                                       float* __restrict__ out) {
    const double* s1 = acc;
    const double* t2 = acc + BSZ;
    const double* s2 = acc + 2 * BSZ;
    const double* s3 = acc + 3 * BSZ;
    const double* s4 = acc + 4 * BSZ;
    int b = threadIdx.x;
    double scale = s1[b] / s2[b];
    double loss = t2[b] - 2.0 * scale * s3[b] + scale * scale * s4[b];
#pragma unroll
    for (int off = 32; off; off >>= 1) loss += __shfl_down(loss, off);
    __shared__ double l[2];
    if ((threadIdx.x & 63) == 0) l[threadIdx.x >> 6] = loss;
    __syncthreads();
    if (threadIdx.x == 0) out[0] = (float)((l[0] + l[1]) / (double)BSZ);
}

extern "C" void kernel_launch(void* const* d_in, const int* in_sizes, int n_in,
                              void* d_out, int out_size, void* d_ws, size_t ws_size,
                              hipStream_t stream) {
    const float* y_pred = (const float*)d_in[0];
    const float* y_true = (const float*)d_in[1];
    const float* vals   = (const float*)d_in[2];
    const int*   rows   = (const int*)d_in[3];
    const int*   cols   = (const int*)d_in[4];
    float* out = (float*)d_out;

    char* ws = (char*)d_ws;
    float*  ypT    = (float*)ws;                         // 128 MB
    double* acc    = (double*)(ws + (size_t)N_GRID * BSZ * 4);
    int*    counts = (int*)((char*)acc + 5 * BSZ * 8);
    int*    ptr    = counts + N_GRID;
    int*    cursor = ptr + N_GRID + 2;
    int*    bsums  = cursor + N_GRID;
    int2*   pairs  = (int2*)(bsums + 512);               // 29.4 MB
    float*  partial = (float*)(pairs + PAIR_CAP);        // 20 MB

    // zero acc + counts (adjacent), and the padded pairs region
    hipMemsetAsync(acc, 0, 5 * BSZ * 8 + (size_t)N_GRID * 4, stream);
    hipMemsetAsync(pairs, 0, (size_t)PAIR_CAP * 8, stream);

    transpose_kernel<<<dim3(N_GRID / 64, BSZ / 64), 256, 0, stream>>>(y_pred, ypT);
    hist_kernel<<<NNZ_TOT / 1024, 256, 0, stream>>>(rows, counts);
    scan1_kernel<<<N_GRID / 512, 512, 0, stream>>>(counts, ptr, bsums);
    scan2_kernel<<<1, 512, 0, stream>>>(bsums, ptr);
    scan3_kernel<<<N_GRID / 512, 512, 0, stream>>>(ptr, cursor, bsums);
    csr_scatter_kernel<<<NNZ_TOT / 1024, 256, 0, stream>>>(vals, rows, cols, cursor, pairs);
    fused_kernel<<<NBLK_FUSED, 256, 0, stream>>>(ypT, y_true, ptr, pairs, partial);
    reduce2_kernel<<<dim3(5, 16), 128, 0, stream>>>(partial, acc);
    finalize_kernel<<<1, 128, 0, stream>>>(acc, out);
}

// Round 2
// 684.366 us; speedup vs baseline: 1.1256x; 1.1256x over previous
//
#include <hip/hip_runtime.h>

#define N_GRID 262144
#define BSZ 128
#define NNZ_TOT 1835008
#define ROWS_PER_BLOCK 32
#define NBLK_FUSED (N_GRID / ROWS_PER_BLOCK)   // 8192
#define PAIR_CAP (NNZ_TOT + 8 * N_GRID)        // min-8 padded worst case = 3932160

typedef float v4f __attribute__((ext_vector_type(4)));
typedef int   v2i __attribute__((ext_vector_type(2)));

// ws layout (8B-aligned):
//   ypT     : N*BSZ f32          = 128 MB  (y_pred transposed)
//   acc     : 5*128 doubles      = 5120 B  (s1, t2, s2, s3, s4)
//   counts  : N ints             = 1 MB
//   ptr     : N+2 ints           = 1 MB    (padded CSR row pointers, every row >= 8 slots)
//   cursor  : N ints             = 1 MB
//   bsums   : 512 ints           = 2 KB
//   pairs   : PAIR_CAP int2      = 31.5 MB (col, bitcast val), row-sorted, zero-padded
//   partial : NBLK_FUSED*640 f32 = 20 MB   (per-block partial sums)

// ---- K1: transpose y_pred (BSZ, N) -> ypT (N, BSZ), float4 both ways ----
// nt loads: yp is read exactly once; keep L3 free for ypT residency.
__global__ __launch_bounds__(256) void transpose_kernel(const float* __restrict__ yp,
                                                        float* __restrict__ ypT) {
    __shared__ float tile[64 * 65];
    int n0 = blockIdx.x * 64;
    int b0 = blockIdx.y * 64;
    int tx = threadIdx.x & 15;   // 0..15 -> 4 floats each
    int ty = threadIdx.x >> 4;   // 0..15
#pragma unroll
    for (int jj = 0; jj < 4; ++jj) {
        int b = b0 + ty + jj * 16;
        v4f v = __builtin_nontemporal_load((const v4f*)&yp[(size_t)b * N_GRID + n0 + 4 * tx]);
        tile[(4 * tx + 0) * 65 + ty + jj * 16] = v.x;
        tile[(4 * tx + 1) * 65 + ty + jj * 16] = v.y;
        tile[(4 * tx + 2) * 65 + ty + jj * 16] = v.z;
        tile[(4 * tx + 3) * 65 + ty + jj * 16] = v.w;
    }
    __syncthreads();
#pragma unroll
    for (int jj = 0; jj < 4; ++jj) {
        int nl = ty + jj * 16;
        v4f v;
        v.x = tile[nl * 65 + 4 * tx + 0];
        v.y = tile[nl * 65 + 4 * tx + 1];
        v.z = tile[nl * 65 + 4 * tx + 2];
        v.w = tile[nl * 65 + 4 * tx + 3];
        *(v4f*)&ypT[(size_t)(n0 + nl) * BSZ + b0 + 4 * tx] = v;  // normal store: want L3-resident
    }
}

// ---- K2: histogram of rows ----
__global__ __launch_bounds__(256) void hist_kernel(const int* __restrict__ rows,
                                                   int* __restrict__ counts) {
    int k0 = blockIdx.x * 1024 + threadIdx.x;
    int kend = blockIdx.x * 1024 + 1024;
#pragma unroll
    for (int k = k0; k < kend; k += 256) {
        int r = __builtin_nontemporal_load(&rows[k]);
        atomicAdd(&counts[r], 1);
    }
}

// ---- K3a: per-block exclusive scan of PADDED counts (512 elems/block) ----
__global__ __launch_bounds__(512) void scan1_kernel(const int* __restrict__ counts,
                                                    int* __restrict__ ptr,
                                                    int* __restrict__ bsums) {
    __shared__ int sdata[512];
    int i = blockIdx.x * 512 + threadIdx.x;
    int x = (counts[i] + 7) & ~7;   // pad each row to a multiple of 8
    if (x < 8) x = 8;               // min 8 slots: makes first chunk unconditional in K5
    sdata[threadIdx.x] = x;
    __syncthreads();
    for (int off = 1; off < 512; off <<= 1) {
        int v = 0;
        if ((int)threadIdx.x >= off) v = sdata[threadIdx.x - off];
        __syncthreads();
        sdata[threadIdx.x] += v;
        __syncthreads();
    }
    ptr[i] = sdata[threadIdx.x] - x;
    if (threadIdx.x == 511) bsums[blockIdx.x] = sdata[511];
}

// ---- K3b: exclusive scan of 512 block sums; grand total -> ptr[N] ----
__global__ __launch_bounds__(512) void scan2_kernel(int* __restrict__ bsums,
                                                    int* __restrict__ ptr) {
    __shared__ int sdata[512];
    int x = bsums[threadIdx.x];
    sdata[threadIdx.x] = x;
    __syncthreads();
    for (int off = 1; off < 512; off <<= 1) {
        int v = 0;
        if ((int)threadIdx.x >= off) v = sdata[threadIdx.x - off];
        __syncthreads();
        sdata[threadIdx.x] += v;
        __syncthreads();
    }
    bsums[threadIdx.x] = sdata[threadIdx.x] - x;
    if (threadIdx.x == 511) ptr[N_GRID] = sdata[511];  // total padded count
}

// ---- K3c: add block offsets, init cursors ----
__global__ __launch_bounds__(512) void scan3_kernel(int* __restrict__ ptr,
                                                    int* __restrict__ cursor,
                                                    const int* __restrict__ bsums) {
    int i = blockIdx.x * 512 + threadIdx.x;
    int v = ptr[i] + bsums[blockIdx.x];
    ptr[i] = v;
    cursor[i] = v;
}

// ---- K4: scatter (col,val) pairs into padded CSR slots ----
__global__ __launch_bounds__(256) void csr_scatter_kernel(const float* __restrict__ vals,
                                                          const int* __restrict__ rows,
                                                          const int* __restrict__ cols,
                                                          int* __restrict__ cursor,
                                                          v2i* __restrict__ pairs) {
    int k0 = blockIdx.x * 1024 + threadIdx.x;
    int kend = blockIdx.x * 1024 + 1024;
#pragma unroll
    for (int k = k0; k < kend; k += 256) {
        int r = __builtin_nontemporal_load(&rows[k]);
        int c = __builtin_nontemporal_load(&cols[k]);
        float v = __builtin_nontemporal_load(&vals[k]);
        int pos = atomicAdd(&cursor[r], 1);
        v2i q; q.x = c; q.y = __float_as_int(v);
        pairs[pos] = q;   // normal store: want pairs L3-resident for K5
    }
}

// 8-wide gather-FMA chunk (tail path)
__device__ __forceinline__ float chunk8(const v2i* __restrict__ pairs, int e,
                                        const float* __restrict__ ypT, int b, float y) {
    v2i q[8];
#pragma unroll
    for (int u = 0; u < 8; ++u) q[u] = pairs[e + u];
    float gv[8];
#pragma unroll
    for (int u = 0; u < 8; ++u) gv[u] = ypT[q[u].x * BSZ + b];
#pragma unroll
    for (int u = 0; u < 8; ++u) y = fmaf(__int_as_float(q[u].y), gv[u], y);
    return y;
}

// ---- K5: fused SpMV + all five per-batch reductions, f32 partials out ----
// 2 rows in flight (16 outstanding gathers/thread); LDS reused for final
// reduction -> 16.5 KB -> 8 blocks/CU.
__global__ __launch_bounds__(256, 8) void fused_kernel(const float* __restrict__ ypT,
                                                       const float* __restrict__ yt,
                                                       const int* __restrict__ ptr,
                                                       const v2i* __restrict__ pairs,
                                                       float* __restrict__ partial) {
    __shared__ __align__(16) float ytile[ROWS_PER_BLOCK * 129];  // 16512 B, reused as red[]
    int b = threadIdx.x & 127;
    int g = threadIdx.x >> 7;  // 0 or 1
    int n0 = blockIdx.x * ROWS_PER_BLOCK;

    for (int idx = threadIdx.x; idx < ROWS_PER_BLOCK * 128; idx += 256) {
        int bb = idx >> 5;
        int j = idx & 31;
        ytile[j * 129 + bb] = __builtin_nontemporal_load(&yt[(size_t)bb * N_GRID + n0 + j]);
    }
    __syncthreads();

    double a1 = 0.0, at2 = 0.0, a2 = 0.0, a3 = 0.0, a4 = 0.0;
    // group g owns rows {g, g+2, ..., g+30}; process two per iteration
    for (int jj = 0; jj < 8; ++jj) {
        int nlA = g + 4 * jj;
        int nlB = nlA + 2;
        int nA = n0 + nlA;
        int nB = n0 + nlB;
        int eA0 = __builtin_amdgcn_readfirstlane(ptr[nA]);
        int eA1 = __builtin_amdgcn_readfirstlane(ptr[nA + 1]);
        int eB0 = __builtin_amdgcn_readfirstlane(ptr[nB]);
        int eB1 = __builtin_amdgcn_readfirstlane(ptr[nB + 1]);
        float pA = ypT[nA * BSZ + b];
        float pB = ypT[nB * BSZ + b];

        // first chunk of both rows, interleaved (every row has >= 8 padded slots)
        v2i qA[8], qB[8];
#pragma unroll
        for (int u = 0; u < 8; ++u) qA[u] = pairs[eA0 + u];
#pragma unroll
        for (int u = 0; u < 8; ++u) qB[u] = pairs[eB0 + u];
        float gA[8], gB[8];
#pragma unroll
        for (int u = 0; u < 8; ++u) gA[u] = ypT[qA[u].x * BSZ + b];
#pragma unroll
        for (int u = 0; u < 8; ++u) gB[u] = ypT[qB[u].x * BSZ + b];
        float yA = 0.0f, yB = 0.0f;
#pragma unroll
        for (int u = 0; u < 8; ++u) yA = fmaf(__int_as_float(qA[u].y), gA[u], yA);
#pragma unroll
        for (int u = 0; u < 8; ++u) yB = fmaf(__int_as_float(qB[u].y), gB[u], yB);
        // rare tails (rows with > 8 entries)
        for (int e = eA0 + 8; e < eA1; e += 8) yA = chunk8(pairs, e, ypT, b, yA);
        for (int e = eB0 + 8; e < eB1; e += 8) yB = chunk8(pairs, e, ypT, b, yB);

        float tA = ytile[nlA * 129 + b];
        float tB = ytile[nlB * 129 + b];
        a1 += (double)tA * (double)pA;  at2 += (double)tA * (double)tA;
        a2 += (double)pA * (double)yA;  a3 += (double)tA * (double)yA;
        a4 += (double)yA * (double)yA;
        a1 += (double)tB * (double)pB;  at2 += (double)tB * (double)tB;
        a2 += (double)pB * (double)yB;  a3 += (double)tB * (double)yB;
        a4 += (double)yB * (double)yB;
    }

    __syncthreads();                       // ytile reads done; reuse as red[]
    double* red = (double*)ytile;          // 5*128*8 = 5120 B <= 16512 B
    if (g == 1) {
        red[b] = a1; red[BSZ + b] = at2; red[2 * BSZ + b] = a2;
        red[3 * BSZ + b] = a3; red[4 * BSZ + b] = a4;
    }
    __syncthreads();
    if (g == 0) {
        float* pb = partial + (size_t)blockIdx.x * (5 * BSZ);
        __builtin_nontemporal_store((float)(a1 + red[b]), &pb[b]);
        __builtin_nontemporal_store((float)(at2 + red[BSZ + b]), &pb[BSZ + b]);
        __builtin_nontemporal_store((float)(a2 + red[2 * BSZ + b]), &pb[2 * BSZ + b]);
        __builtin_nontemporal_store((float)(a3 + red[3 * BSZ + b]), &pb[3 * BSZ + b]);
        __builtin_nontemporal_store((float)(a4 + red[4 * BSZ + b]), &pb[4 * BSZ + b]);
    }
}

// ---- K6: reduce partials into acc (grid: (5, 16), 128 threads) ----
__global__ __launch_bounds__(128) void reduce2_kernel(const float* __restrict__ partial,
                                                      double* __restrict__ acc) {
    int s = blockIdx.x;
    int chunk = blockIdx.y;
    int b = threadIdx.x;
    const int PER = NBLK_FUSED / 16;  // 512
    double sum = 0.0;
    int i0 = chunk * PER;
#pragma unroll 4
    for (int i = 0; i < PER; ++i) {
        sum += (double)__builtin_nontemporal_load(
            &partial[(size_t)(i0 + i) * (5 * BSZ) + s * BSZ + b]);
    }
    atomicAdd(&acc[s * BSZ + b], sum);
}

// ---- K7: loss_b = t2 - 2*scale*s3 + scale^2*s4; out = mean_b ----
__global__ __launch_bounds__(128) void finalize_kernel(const double* __restrict__ acc,
                                                       float* __restrict__ out) {
    const double* s1 = acc;
    const double* t2 = acc + BSZ;
    const double* s2 = acc + 2 * BSZ;
    const double* s3 = acc + 3 * BSZ;
    const double* s4 = acc + 4 * BSZ;
    int b = threadIdx.x;
    double scale = s1[b] / s2[b];
    double loss = t2[b] - 2.0 * scale * s3[b] + scale * scale * s4[b];
#pragma unroll
    for (int off = 32; off; off >>= 1) loss += __shfl_down(loss, off);
    __shared__ double l[2];
    if ((threadIdx.x & 63) == 0) l[threadIdx.x >> 6] = loss;
    __syncthreads();
    if (threadIdx.x == 0) out[0] = (float)((l[0] + l[1]) / (double)BSZ);
}

extern "C" void kernel_launch(void* const* d_in, const int* in_sizes, int n_in,
                              void* d_out, int out_size, void* d_ws, size_t ws_size,
                              hipStream_t stream) {
    const float* y_pred = (const float*)d_in[0];
    const float* y_true = (const float*)d_in[1];
    const float* vals   = (const float*)d_in[2];
    const int*   rows   = (const int*)d_in[3];
    const int*   cols   = (const int*)d_in[4];
    float* out = (float*)d_out;

    char* ws = (char*)d_ws;
    float*  ypT    = (float*)ws;                         // 128 MB
    double* acc    = (double*)(ws + (size_t)N_GRID * BSZ * 4);
    int*    counts = (int*)((char*)acc + 5 * BSZ * 8);
    int*    ptr    = counts + N_GRID;
    int*    cursor = ptr + N_GRID + 2;
    int*    bsums  = cursor + N_GRID;
    v2i*    pairs  = (v2i*)(bsums + 512);                // 31.5 MB
    float*  partial = (float*)(pairs + PAIR_CAP);        // 20 MB

    // zero acc + counts (adjacent), and the padded pairs region
    hipMemsetAsync(acc, 0, 5 * BSZ * 8 + (size_t)N_GRID * 4, stream);
    hipMemsetAsync(pairs, 0, (size_t)PAIR_CAP * 8, stream);

    transpose_kernel<<<dim3(N_GRID / 64, BSZ / 64), 256, 0, stream>>>(y_pred, ypT);
    hist_kernel<<<NNZ_TOT / 1024, 256, 0, stream>>>(rows, counts);
    scan1_kernel<<<N_GRID / 512, 512, 0, stream>>>(counts, ptr, bsums);
    scan2_kernel<<<1, 512, 0, stream>>>(bsums, ptr);
    scan3_kernel<<<N_GRID / 512, 512, 0, stream>>>(ptr, cursor, bsums);
    csr_scatter_kernel<<<NNZ_TOT / 1024, 256, 0, stream>>>(vals, rows, cols, cursor, pairs);
    fused_kernel<<<NBLK_FUSED, 256, 0, stream>>>(ypT, y_true, ptr, pairs, partial);
    reduce2_kernel<<<dim3(5, 16), 128, 0, stream>>>(partial, acc);
    finalize_kernel<<<1, 128, 0, stream>>>(acc, out);
}

// Round 3
// 638.278 us; speedup vs baseline: 1.2069x; 1.0722x over previous
//
#include <hip/hip_runtime.h>

#define N_GRID 262144
#define BSZ 128
#define NNZ_TOT 1835008
#define ROWS_PER_BLOCK 32
#define NBLK_FUSED (N_GRID / ROWS_PER_BLOCK)   // 8192
#define PAIR_CAP (NNZ_TOT + 8 * N_GRID)        // min-8 padded worst case = 3932160
#define PARTIAL_STRIDE (5 * 64)                // floats per block per half-batch

typedef float v4f __attribute__((ext_vector_type(4)));
typedef int   v2i __attribute__((ext_vector_type(2)));

// ws layout (8B-aligned):
//   ypT     : N*BSZ f32            = 128 MB  (y_pred transposed)
//   acc     : 5*128 doubles        = 5120 B  (s1, t2, s2, s3, s4)
//   counts  : N ints               = 1 MB
//   ptr     : N+2 ints             = 1 MB    (padded CSR row pointers, every row >= 8 slots)
//   bsums   : 512 ints             = 2 KB
//   pairs   : PAIR_CAP int2        = 31.5 MB (col, bitcast val), row-sorted, zero-padded
//   partial : 2*NBLK_FUSED*320 f32 = 21 MB   (per-block partials, 2 half-batches)
//   rank    : overlays partial     = 7.3 MB  (per-nonzero rank within row; dead before fused)

// ---- K1: transpose y_pred (BSZ, N) -> ypT (N, BSZ), float4 both ways ----
__global__ __launch_bounds__(256) void transpose_kernel(const float* __restrict__ yp,
                                                        float* __restrict__ ypT) {
    __shared__ float tile[64 * 65];
    int n0 = blockIdx.x * 64;
    int b0 = blockIdx.y * 64;
    int tx = threadIdx.x & 15;   // 0..15 -> 4 floats each
    int ty = threadIdx.x >> 4;   // 0..15
#pragma unroll
    for (int jj = 0; jj < 4; ++jj) {
        int b = b0 + ty + jj * 16;
        v4f v = __builtin_nontemporal_load((const v4f*)&yp[(size_t)b * N_GRID + n0 + 4 * tx]);
        tile[(4 * tx + 0) * 65 + ty + jj * 16] = v.x;
        tile[(4 * tx + 1) * 65 + ty + jj * 16] = v.y;
        tile[(4 * tx + 2) * 65 + ty + jj * 16] = v.z;
        tile[(4 * tx + 3) * 65 + ty + jj * 16] = v.w;
    }
    __syncthreads();
#pragma unroll
    for (int jj = 0; jj < 4; ++jj) {
        int nl = ty + jj * 16;
        v4f v;
        v.x = tile[nl * 65 + 4 * tx + 0];
        v.y = tile[nl * 65 + 4 * tx + 1];
        v.z = tile[nl * 65 + 4 * tx + 2];
        v.w = tile[nl * 65 + 4 * tx + 3];
        *(v4f*)&ypT[(size_t)(n0 + nl) * BSZ + b0 + 4 * tx] = v;  // normal store: want L3-resident
    }
}

// ---- K2: histogram of rows + per-entry rank (removes the scatter-side atomic) ----
__global__ __launch_bounds__(256) void hist_kernel(const int* __restrict__ rows,
                                                   int* __restrict__ counts,
                                                   int* __restrict__ rank) {
    int k0 = blockIdx.x * 1024 + threadIdx.x;
    int kend = blockIdx.x * 1024 + 1024;
#pragma unroll
    for (int k = k0; k < kend; k += 256) {
        int r = __builtin_nontemporal_load(&rows[k]);
        int rk = atomicAdd(&counts[r], 1);
        __builtin_nontemporal_store(rk, &rank[k]);
    }
}

// ---- K3a: per-block exclusive scan of PADDED counts (512 elems/block) ----
__global__ __launch_bounds__(512) void scan1_kernel(const int* __restrict__ counts,
                                                    int* __restrict__ ptr,
                                                    int* __restrict__ bsums) {
    __shared__ int sdata[512];
    int i = blockIdx.x * 512 + threadIdx.x;
    int x = (counts[i] + 7) & ~7;   // pad each row to a multiple of 8
    if (x < 8) x = 8;               // min 8 slots: makes first chunk unconditional in K5
    sdata[threadIdx.x] = x;
    __syncthreads();
    for (int off = 1; off < 512; off <<= 1) {
        int v = 0;
        if ((int)threadIdx.x >= off) v = sdata[threadIdx.x - off];
        __syncthreads();
        sdata[threadIdx.x] += v;
        __syncthreads();
    }
    ptr[i] = sdata[threadIdx.x] - x;
    if (threadIdx.x == 511) bsums[blockIdx.x] = sdata[511];
}

// ---- K3b: exclusive scan of 512 block sums; grand total -> ptr[N] ----
__global__ __launch_bounds__(512) void scan2_kernel(int* __restrict__ bsums,
                                                    int* __restrict__ ptr) {
    __shared__ int sdata[512];
    int x = bsums[threadIdx.x];
    sdata[threadIdx.x] = x;
    __syncthreads();
    for (int off = 1; off < 512; off <<= 1) {
        int v = 0;
        if ((int)threadIdx.x >= off) v = sdata[threadIdx.x - off];
        __syncthreads();
        sdata[threadIdx.x] += v;
        __syncthreads();
    }
    bsums[threadIdx.x] = sdata[threadIdx.x] - x;
    if (threadIdx.x == 511) ptr[N_GRID] = sdata[511];  // total padded count
}

// ---- K3c: add block offsets ----
__global__ __launch_bounds__(512) void scan3_kernel(int* __restrict__ ptr,
                                                    const int* __restrict__ bsums) {
    int i = blockIdx.x * 512 + threadIdx.x;
    ptr[i] = ptr[i] + bsums[blockIdx.x];
}

// ---- K4: scatter (col,val) pairs into padded CSR slots; atomic-free ----
__global__ __launch_bounds__(256) void csr_scatter_kernel(const float* __restrict__ vals,
                                                          const int* __restrict__ rows,
                                                          const int* __restrict__ cols,
                                                          const int* __restrict__ ptr,
                                                          const int* __restrict__ rank,
                                                          v2i* __restrict__ pairs) {
    int k0 = blockIdx.x * 1024 + threadIdx.x;
    int kend = blockIdx.x * 1024 + 1024;
#pragma unroll
    for (int k = k0; k < kend; k += 256) {
        int r = __builtin_nontemporal_load(&rows[k]);
        int c = __builtin_nontemporal_load(&cols[k]);
        float v = __builtin_nontemporal_load(&vals[k]);
        int rk = __builtin_nontemporal_load(&rank[k]);
        int pos = ptr[r] + rk;   // ptr is 1 MB, stays cached
        v2i q; q.x = c; q.y = __float_as_int(v);
        pairs[pos] = q;          // normal store: want pairs L3-resident for K5
    }
}

// 8-wide gather-FMA chunk (tail path)
__device__ __forceinline__ float chunk8(const v2i* __restrict__ pairs, int e,
                                        const float* __restrict__ ypT, int B, float y) {
    v2i q[8];
#pragma unroll
    for (int u = 0; u < 8; ++u) q[u] = pairs[e + u];
    float gv[8];
#pragma unroll
    for (int u = 0; u < 8; ++u) gv[u] = ypT[q[u].x * BSZ + B];
#pragma unroll
    for (int u = 0; u < 8; ++u) y = fmaf(__int_as_float(q[u].y), gv[u], y);
    return y;
}

// ---- K5: fused SpMV + reductions over a 64-wide HALF of the batch ----
// Two sequential launches (b0 = 0, 64): per-pass gather target = 67 MB -> L3-resident.
// 4 row-groups x 64 batch lanes; 2 rows in flight (16 outstanding gathers/thread).
__global__ __launch_bounds__(256, 8) void fused_kernel(const float* __restrict__ ypT,
                                                       const float* __restrict__ yt,
                                                       const int* __restrict__ ptr,
                                                       const v2i* __restrict__ pairs,
                                                       float* __restrict__ partial,
                                                       int b0) {
    __shared__ __align__(16) char smem[ROWS_PER_BLOCK * 65 * 4];  // 8320 B; reused as red[]
    float* ytile = (float*)smem;
    int b = threadIdx.x & 63;
    int g = threadIdx.x >> 6;  // 0..3
    int B = b0 + b;            // global batch index
    int n0 = blockIdx.x * ROWS_PER_BLOCK;

    for (int idx = threadIdx.x; idx < ROWS_PER_BLOCK * 64; idx += 256) {
        int bb = idx >> 5;   // 0..63 local batch
        int j = idx & 31;    // row within tile
        ytile[j * 65 + bb] = __builtin_nontemporal_load(&yt[(size_t)(b0 + bb) * N_GRID + n0 + j]);
    }
    __syncthreads();

    double a1 = 0.0, at2 = 0.0, a2 = 0.0, a3 = 0.0, a4 = 0.0;
    // group g owns rows {g, g+4, ..., g+28}; process two per iteration
    for (int jj = 0; jj < 4; ++jj) {
        int nlA = g + 8 * jj;
        int nlB = nlA + 4;
        int nA = n0 + nlA;
        int nB = n0 + nlB;
        int eA0 = __builtin_amdgcn_readfirstlane(ptr[nA]);
        int eA1 = __builtin_amdgcn_readfirstlane(ptr[nA + 1]);
        int eB0 = __builtin_amdgcn_readfirstlane(ptr[nB]);
        int eB1 = __builtin_amdgcn_readfirstlane(ptr[nB + 1]);
        float pA = ypT[nA * BSZ + B];
        float pB = ypT[nB * BSZ + B];

        // first chunk of both rows, interleaved (every row has >= 8 padded slots)
        v2i qA[8], qB[8];
#pragma unroll
        for (int u = 0; u < 8; ++u) qA[u] = pairs[eA0 + u];
#pragma unroll
        for (int u = 0; u < 8; ++u) qB[u] = pairs[eB0 + u];
        float gA[8], gB[8];
#pragma unroll
        for (int u = 0; u < 8; ++u) gA[u] = ypT[qA[u].x * BSZ + B];
#pragma unroll
        for (int u = 0; u < 8; ++u) gB[u] = ypT[qB[u].x * BSZ + B];
        float yA = 0.0f, yB = 0.0f;
#pragma unroll
        for (int u = 0; u < 8; ++u) yA = fmaf(__int_as_float(qA[u].y), gA[u], yA);
#pragma unroll
        for (int u = 0; u < 8; ++u) yB = fmaf(__int_as_float(qB[u].y), gB[u], yB);
        // rare tails (rows with > 8 entries)
        for (int e = eA0 + 8; e < eA1; e += 8) yA = chunk8(pairs, e, ypT, B, yA);
        for (int e = eB0 + 8; e < eB1; e += 8) yB = chunk8(pairs, e, ypT, B, yB);

        float tA = ytile[nlA * 65 + b];
        float tB = ytile[nlB * 65 + b];
        a1 += (double)tA * (double)pA;  at2 += (double)tA * (double)tA;
        a2 += (double)pA * (double)yA;  a3 += (double)tA * (double)yA;
        a4 += (double)yA * (double)yA;
        a1 += (double)tB * (double)pB;  at2 += (double)tB * (double)tB;
        a2 += (double)pB * (double)yB;  a3 += (double)tB * (double)yB;
        a4 += (double)yB * (double)yB;
    }

    __syncthreads();                    // ytile reads done; reuse as red[]
    double* red = (double*)smem;        // 5 sums x 3 groups x 64 lanes = 7680 B <= 8320 B
    if (g > 0) {
        int gg = g - 1;
        red[0 * 192 + gg * 64 + b] = a1;
        red[1 * 192 + gg * 64 + b] = at2;
        red[2 * 192 + gg * 64 + b] = a2;
        red[3 * 192 + gg * 64 + b] = a3;
        red[4 * 192 + gg * 64 + b] = a4;
    }
    __syncthreads();
    if (g == 0) {
        float* pb = partial + (size_t)(b0 >> 6) * NBLK_FUSED * PARTIAL_STRIDE
                            + (size_t)blockIdx.x * PARTIAL_STRIDE;
        double r0 = a1  + red[0 * 192 + b] + red[0 * 192 + 64 + b] + red[0 * 192 + 128 + b];
        double r1 = at2 + red[1 * 192 + b] + red[1 * 192 + 64 + b] + red[1 * 192 + 128 + b];
        double r2 = a2  + red[2 * 192 + b] + red[2 * 192 + 64 + b] + red[2 * 192 + 128 + b];
        double r3 = a3  + red[3 * 192 + b] + red[3 * 192 + 64 + b] + red[3 * 192 + 128 + b];
        double r4 = a4  + red[4 * 192 + b] + red[4 * 192 + 64 + b] + red[4 * 192 + 128 + b];
        __builtin_nontemporal_store((float)r0, &pb[0 * 64 + b]);
        __builtin_nontemporal_store((float)r1, &pb[1 * 64 + b]);
        __builtin_nontemporal_store((float)r2, &pb[2 * 64 + b]);
        __builtin_nontemporal_store((float)r3, &pb[3 * 64 + b]);
        __builtin_nontemporal_store((float)r4, &pb[4 * 64 + b]);
    }
}

// ---- K6: reduce partials into acc (grid: (5, 16), 128 threads) ----
__global__ __launch_bounds__(128) void reduce2_kernel(const float* __restrict__ partial,
                                                      double* __restrict__ acc) {
    int s = blockIdx.x;
    int chunk = blockIdx.y;
    int b = threadIdx.x;          // global batch index 0..127
    int half = b >> 6;
    int bl = b & 63;
    const float* P = partial + (size_t)half * NBLK_FUSED * PARTIAL_STRIDE;
    const int PER = NBLK_FUSED / 16;  // 512
    double sum = 0.0;
    int i0 = chunk * PER;
#pragma unroll 4
    for (int i = 0; i < PER; ++i) {
        sum += (double)__builtin_nontemporal_load(
            &P[(size_t)(i0 + i) * PARTIAL_STRIDE + s * 64 + bl]);
    }
    atomicAdd(&acc[s * BSZ + b], sum);
}

// ---- K7: loss_b = t2 - 2*scale*s3 + scale^2*s4; out = mean_b ----
__global__ __launch_bounds__(128) void finalize_kernel(const double* __restrict__ acc,
                                                       float* __restrict__ out) {
    const double* s1 = acc;
    const double* t2 = acc + BSZ;
    const double* s2 = acc + 2 * BSZ;
    const double* s3 = acc + 3 * BSZ;
    const double* s4 = acc + 4 * BSZ;
    int b = threadIdx.x;
    double scale = s1[b] / s2[b];
    double loss = t2[b] - 2.0 * scale * s3[b] + scale * scale * s4[b];
#pragma unroll
    for (int off = 32; off; off >>= 1) loss += __shfl_down(loss, off);
    __shared__ double l[2];
    if ((threadIdx.x & 63) == 0) l[threadIdx.x >> 6] = loss;
    __syncthreads();
    if (threadIdx.x == 0) out[0] = (float)((l[0] + l[1]) / (double)BSZ);
}

extern "C" void kernel_launch(void* const* d_in, const int* in_sizes, int n_in,
                              void* d_out, int out_size, void* d_ws, size_t ws_size,
                              hipStream_t stream) {
    const float* y_pred = (const float*)d_in[0];
    const float* y_true = (const float*)d_in[1];
    const float* vals   = (const float*)d_in[2];
    const int*   rows   = (const int*)d_in[3];
    const int*   cols   = (const int*)d_in[4];
    float* out = (float*)d_out;

    char* ws = (char*)d_ws;
    float*  ypT    = (float*)ws;                         // 128 MB
    double* acc    = (double*)(ws + (size_t)N_GRID * BSZ * 4);
    int*    counts = (int*)((char*)acc + 5 * BSZ * 8);
    int*    ptr    = counts + N_GRID;
    int*    bsums  = ptr + N_GRID + 2;
    v2i*    pairs  = (v2i*)(bsums + 512);                // 31.5 MB
    float*  partial = (float*)(pairs + PAIR_CAP);        // 21 MB (2 halves)
    int*    rank   = (int*)partial;                      // 7.3 MB overlay; dead before fused

    // zero acc + counts (adjacent), and the padded pairs region
    hipMemsetAsync(acc, 0, 5 * BSZ * 8 + (size_t)N_GRID * 4, stream);
    hipMemsetAsync(pairs, 0, (size_t)PAIR_CAP * 8, stream);

    transpose_kernel<<<dim3(N_GRID / 64, BSZ / 64), 256, 0, stream>>>(y_pred, ypT);
    hist_kernel<<<NNZ_TOT / 1024, 256, 0, stream>>>(rows, counts, rank);
    scan1_kernel<<<N_GRID / 512, 512, 0, stream>>>(counts, ptr, bsums);
    scan2_kernel<<<1, 512, 0, stream>>>(bsums, ptr);
    scan3_kernel<<<N_GRID / 512, 512, 0, stream>>>(ptr, bsums);
    csr_scatter_kernel<<<NNZ_TOT / 1024, 256, 0, stream>>>(vals, rows, cols, ptr, rank, pairs);
    fused_kernel<<<NBLK_FUSED, 256, 0, stream>>>(ypT, y_true, ptr, pairs, partial, 0);
    fused_kernel<<<NBLK_FUSED, 256, 0, stream>>>(ypT, y_true, ptr, pairs, partial, 64);
    reduce2_kernel<<<dim3(5, 16), 128, 0, stream>>>(partial, acc);
    finalize_kernel<<<1, 128, 0, stream>>>(acc, out);
}